// Round 3
// baseline (1205.731 us; speedup 1.0000x reference)
//
#include <hip/hip_runtime.h>
#include <math.h>

#define NB 8            // batch
#define JJ 421          // J = 5*81 + 16
#define HDCN 256        // HDC
#define PP (JJ*HDCN)    // 107776 pixels per (batch,channel) plane
#define STEPS 20

typedef __attribute__((ext_vector_type(8))) short bf16x8;
typedef __attribute__((ext_vector_type(4))) float f32x4;
typedef unsigned short ushort;
typedef unsigned int uint;

__device__ __forceinline__ ushort f2bf(float f) {
    union { float f; uint u; } a; a.f = f;
    uint r = 0x7fffu + ((a.u >> 16) & 1u);     // round-to-nearest-even
    return (ushort)((a.u + r) >> 16);
}
__device__ __forceinline__ float bf2f(ushort h) {
    union { uint u; float f; } a; a.u = ((uint)h) << 16;
    return a.f;
}

__device__ __forceinline__ float wave_reduce_sum(float v) {
#pragma unroll
    for (int off = 32; off > 0; off >>= 1) v += __shfl_down(v, off);
    return v;
}

// ---------------------------------------------------------------------------
// k_prep: s[b] = sum_i data[b,i]  where data = concat(data_input, structure, pe)
// ---------------------------------------------------------------------------
__global__ __launch_bounds__(128) void k_prep(
    const float* __restrict__ din, const float* __restrict__ stin,
    const float* __restrict__ m_in, const float* __restrict__ m_out,
    float* __restrict__ sbuf)
{
    int b = blockIdx.x, t = threadIdx.x;
    float acc = 0.f;
    for (int k = t; k < 324; k += 128) acc += din[b * 324 + k];
    for (int k = t; k < 81;  k += 128) acc += stin[b * 81 + k];
    if (t < 16) {
        int i = t;
        float pos_in  = m_in[b]  * 0.01f;
        float pos_out = m_out[b] * 0.01f;
        float div = powf(10000.0f, (float)(2 * (i / 2)) / 16.0f);
        float ai = pos_in / div, ao = pos_out / div;
        float v = ((i & 1) == 0) ? 0.5f * (sinf(ai) + cosf(ai))
                                 : 0.5f * (cosf(ai) + sinf(ao));
        acc += v;
    }
    __shared__ float part[2];
    float w = wave_reduce_sum(acc);
    if ((t & 63) == 0) part[t >> 6] = w;
    __syncthreads();
    if (t == 0) sbuf[b] = part[0] + part[1];
}

// ---------------------------------------------------------------------------
// k_x0: x0[b,o,jd] = tanh( A - 2p*B + p^2*C + cb[o] );  128 thr, 842 blocks
// ---------------------------------------------------------------------------
__global__ __launch_bounds__(128) void k_x0(
    const float* __restrict__ rbf, const float* __restrict__ hdc,
    const float* __restrict__ cw, const float* __restrict__ cb,
    const float* __restrict__ sbuf, float* __restrict__ x0)
{
    __shared__ float wl[320];
    __shared__ float Cw[5];
    __shared__ float sb[8];
    __shared__ float cbs[5];
    int t = threadIdx.x;
    for (int k = t; k < 320; k += 128) wl[k] = cw[k];
    if (t < 8)   sb[t] = sbuf[t];
    if (t < 5)   cbs[t] = cb[t];
    __syncthreads();
    if (t < 5) { float c = 0.f; for (int r = 0; r < 64; ++r) c += wl[t * 64 + r]; Cw[t] = c; }
    __syncthreads();

    int jd = blockIdx.x * 128 + t;       // 842*128 == PP exactly
    float A[5]  = {0, 0, 0, 0, 0};
    float Bv[5] = {0, 0, 0, 0, 0};
    for (int r = 0; r < 64; ++r) {
        float v  = rbf[(size_t)r * PP + jd];
        float v2 = v * v;
#pragma unroll
        for (int o = 0; o < 5; ++o) {
            float w = wl[o * 64 + r];
            A[o]  = fmaf(w, v2, A[o]);
            Bv[o] = fmaf(w, v,  Bv[o]);
        }
    }
#pragma unroll
    for (int b = 0; b < 8; ++b) {
        float p  = sb[b] * hdc[(size_t)b * PP + jd];
        float p2 = p * p;
#pragma unroll
        for (int o = 0; o < 5; ++o) {
            float val = A[o] - 2.f * p * Bv[o] + p2 * Cw[o] + cbs[o];
            x0[(size_t)(b * 5 + o) * PP + jd] = tanhf(val);
        }
    }
}

// ---------------------------------------------------------------------------
// k_nca (MFMA): one NCA step for one (b, j) row of 256 pixels.
//   conv3x3 5->32 as GEMM: M=32 oc, K=45 taps (k = c*9+dj*3+dd), N=256 px.
//   Precision: x = xh+xl (bf16 pair), w1 = wh+wl; terms wh*xh + wh*xl + wl*xh.
//   im2col in LDS: Bs[px][128k] bf16 ([xh 64 | xl 64]), XOR-swizzled rows.
//   Projection W2[5,32] + bias + residual in exact fp32 VALU from D-frags.
// ---------------------------------------------------------------------------
__global__ __launch_bounds__(256) void k_nca(
    const float* __restrict__ xin, float* __restrict__ xout,
    const float* __restrict__ w1, const float* __restrict__ b1,
    const float* __restrict__ w2, const float* __restrict__ b2)
{
    __shared__ __align__(16) char Bs[256 * 256];  // 64 KB: [px][128k]*2B
    __shared__ __align__(16) char As[32 * 256];   //  8 KB: [oc][128k]*2B

    const int t = threadIdx.x;
    const int b = blockIdx.x & 7;
    const int j = blockIdx.x >> 3;

    // ---- build A: wh at k-bytes [0,128), wl at [128,256), pad k>=45 zero ----
    for (int idx = t; idx < 32 * 64; idx += 256) {
        int oc = idx >> 6, k = idx & 63;
        float v = (k < 45) ? w1[oc * 45 + k] : 0.f;
        ushort hi = f2bf(v);
        ushort lo = f2bf(v - bf2f(hi));
        int rb = oc << 8;
        int sw = (oc & 7) << 4;
        *(ushort*)(As + ((rb + 2 * k) ^ sw))       = hi;
        *(ushort*)(As + ((rb + 128 + 2 * k) ^ sw)) = lo;
    }

    // ---- build B: thread t owns pixel px=t (its own wave consumes it) ----
    {
        const float* xb = xin + (size_t)b * 5 * PP;
        const int sw = (t & 7) << 4;
        const int rb = t << 8;
        for (int g6 = 0; g6 < 6; ++g6) {
            ushort hb[8], lb[8];
#pragma unroll
            for (int kk = 0; kk < 8; ++kk) {
                int k = g6 * 8 + kk;
                float v = 0.f;
                if (k < 45) {
                    int c = k / 9, rem = k % 9;
                    int dj = rem / 3, dd = rem % 3;
                    int jj = j + dj - 1;
                    int dcol = t + dd - 1;
                    if (jj >= 0 && jj < JJ && dcol >= 0 && dcol < HDCN)
                        v = xb[((size_t)c * JJ + jj) * HDCN + dcol];
                }
                ushort hi = f2bf(v);
                hb[kk] = hi;
                lb[kk] = f2bf(v - bf2f(hi));
            }
            uint4 ph, pl;
            ph.x = hb[0] | ((uint)hb[1] << 16); ph.y = hb[2] | ((uint)hb[3] << 16);
            ph.z = hb[4] | ((uint)hb[5] << 16); ph.w = hb[6] | ((uint)hb[7] << 16);
            pl.x = lb[0] | ((uint)lb[1] << 16); pl.y = lb[2] | ((uint)lb[3] << 16);
            pl.z = lb[4] | ((uint)lb[5] << 16); pl.w = lb[6] | ((uint)lb[7] << 16);
            *(uint4*)(Bs + ((rb + g6 * 16) ^ sw))       = ph;
            *(uint4*)(Bs + ((rb + 128 + g6 * 16) ^ sw)) = pl;
        }
        uint4 z = {0, 0, 0, 0};
        *(uint4*)(Bs + ((rb + 96) ^ sw))  = z;   // xh pad k 48..63
        *(uint4*)(Bs + ((rb + 112) ^ sw)) = z;
        *(uint4*)(Bs + ((rb + 224) ^ sw)) = z;   // xl pad
        *(uint4*)(Bs + ((rb + 240) ^ sw)) = z;
    }

    // ---- per-lane W2 / b1 / b2 (exact fp32) ----
    const int lane = t & 63, wv = t >> 6;
    const int m = lane & 15, gq = lane >> 4;
    float w2r[2][4][5], b1r[2][4], b2r[5];
#pragma unroll
    for (int mt = 0; mt < 2; ++mt)
#pragma unroll
        for (int i = 0; i < 4; ++i) {
            int oc = mt * 16 + gq * 4 + i;
            b1r[mt][i] = b1[oc];
#pragma unroll
            for (int o = 0; o < 5; ++o) w2r[mt][i][o] = w2[o * 32 + oc];
        }
#pragma unroll
    for (int o = 0; o < 5; ++o) b2r[o] = b2[o];

    __syncthreads();

    // ---- A fragments: lane m = oc row within tile, 8 contiguous k at gq*8 ----
    bf16x8 Awh[2][2], Awl[2][2];
#pragma unroll
    for (int mt = 0; mt < 2; ++mt)
#pragma unroll
        for (int ks = 0; ks < 2; ++ks) {
            int oc = mt * 16 + m;
            int sw = (oc & 7) << 4;
            Awh[mt][ks] = *(const bf16x8*)(As + (((oc << 8) + ks * 64 + gq * 16) ^ sw));
            Awl[mt][ks] = *(const bf16x8*)(As + (((oc << 8) + 128 + ks * 64 + gq * 16) ^ sw));
        }

    f32x4 acc[2][4];
#pragma unroll
    for (int mt = 0; mt < 2; ++mt)
#pragma unroll
        for (int nt = 0; nt < 4; ++nt) acc[mt][nt] = (f32x4){0.f, 0.f, 0.f, 0.f};

    // ---- conv MFMAs: ks 0..1 = xh (pair with wh AND wl), ks 2..3 = xl (wh) ----
#pragma unroll
    for (int nt = 0; nt < 4; ++nt) {
        int px = wv * 64 + nt * 16 + m;
        int sw = (px & 7) << 4;
        int rb = px << 8;
#pragma unroll
        for (int ks = 0; ks < 4; ++ks) {
            bf16x8 Bf = *(const bf16x8*)(Bs + ((rb + ks * 64 + gq * 16) ^ sw));
            if (ks < 2) {
                acc[0][nt] = __builtin_amdgcn_mfma_f32_16x16x32_bf16(Awh[0][ks], Bf, acc[0][nt], 0, 0, 0);
                acc[1][nt] = __builtin_amdgcn_mfma_f32_16x16x32_bf16(Awh[1][ks], Bf, acc[1][nt], 0, 0, 0);
                acc[0][nt] = __builtin_amdgcn_mfma_f32_16x16x32_bf16(Awl[0][ks], Bf, acc[0][nt], 0, 0, 0);
                acc[1][nt] = __builtin_amdgcn_mfma_f32_16x16x32_bf16(Awl[1][ks], Bf, acc[1][nt], 0, 0, 0);
            } else {
                acc[0][nt] = __builtin_amdgcn_mfma_f32_16x16x32_bf16(Awh[0][ks - 2], Bf, acc[0][nt], 0, 0, 0);
                acc[1][nt] = __builtin_amdgcn_mfma_f32_16x16x32_bf16(Awh[1][ks - 2], Bf, acc[1][nt], 0, 0, 0);
            }
        }
    }

    // ---- epilogue: h = relu(conv + b1); dx = W2 h; cross-gq reduce; residual ----
    const size_t base_bj = (size_t)b * 5 * PP + (size_t)j * HDCN;
#pragma unroll
    for (int nt = 0; nt < 4; ++nt) {
        int px = wv * 64 + nt * 16 + m;
        float dx[5] = {0, 0, 0, 0, 0};
#pragma unroll
        for (int mt = 0; mt < 2; ++mt)
#pragma unroll
            for (int i = 0; i < 4; ++i) {
                float h = acc[mt][nt][i] + b1r[mt][i];
                h = fmaxf(h, 0.f);
#pragma unroll
                for (int o = 0; o < 5; ++o) dx[o] = fmaf(w2r[mt][i][o], h, dx[o]);
            }
#pragma unroll
        for (int o = 0; o < 5; ++o) {
            dx[o] += __shfl_xor(dx[o], 16);
            dx[o] += __shfl_xor(dx[o], 32);
        }
        if (gq == 0) {
#pragma unroll
            for (int o = 0; o < 4; ++o) {
                size_t idx = base_bj + (size_t)o * PP + px;
                xout[idx] = xin[idx] + dx[o] + b2r[o];
            }
        } else if (gq == 1) {
            size_t idx = base_bj + (size_t)4 * PP + px;
            xout[idx] = xin[idx] + dx[4] + b2r[4];
        }
    }
}

// ---------------------------------------------------------------------------
// k_mean: m[bc,j] = mean_d tanh(x[bc,j,d])
// ---------------------------------------------------------------------------
__global__ __launch_bounds__(256) void k_mean(
    const float* __restrict__ x, float* __restrict__ m)
{
    int idx = blockIdx.x;
    int t = threadIdx.x;
    float v = tanhf(x[(size_t)idx * HDCN + t]);
    __shared__ float part[4];
    float w = wave_reduce_sum(v);
    if ((t & 63) == 0) part[t >> 6] = w;
    __syncthreads();
    if (t == 0) m[idx] = (part[0] + part[1] + part[2] + part[3]) * (1.0f / 256.0f);
}

// ---------------------------------------------------------------------------
// k_out: adaptive pool J=421 -> 81, outputs concat(r,g,b,a,s)
// ---------------------------------------------------------------------------
__global__ __launch_bounds__(256) void k_out(
    const float* __restrict__ m, float* __restrict__ out)
{
    int idx = blockIdx.x * 256 + threadIdx.x;
    if (idx >= 5 * NB * 81) return;
    int c = idx / (NB * 81);
    int rem = idx % (NB * 81);
    int b = rem / 81;
    int o = rem % 81;
    int s_ = (o * JJ) / 81;
    int e_ = ((o + 1) * JJ + 80) / 81;
    float acc = 0.f;
    for (int jj = s_; jj < e_; ++jj) acc += m[(b * 5 + c) * JJ + jj];
    out[idx] = acc / (float)(e_ - s_);
}

// ---------------------------------------------------------------------------
extern "C" void kernel_launch(void* const* d_in, const int* in_sizes, int n_in,
                              void* d_out, int out_size, void* d_ws, size_t ws_size,
                              hipStream_t stream) {
    const float* data_in  = (const float*)d_in[0];
    const float* struc_in = (const float*)d_in[1];
    const float* meta_in  = (const float*)d_in[2];
    const float* meta_out = (const float*)d_in[3];
    const float* rbf      = (const float*)d_in[4];
    const float* hdc      = (const float*)d_in[5];
    const float* cw       = (const float*)d_in[6];
    const float* cb       = (const float*)d_in[7];
    const float* w1       = (const float*)d_in[8];
    const float* b1       = (const float*)d_in[9];
    const float* w2       = (const float*)d_in[10];
    const float* b2       = (const float*)d_in[11];
    float* out = (float*)d_out;

    float* ws   = (float*)d_ws;
    float* sbuf = ws;                       // 8 floats
    float* mbuf = ws + 64;                  // 40*421 floats
    float* xA   = ws + 32768;               // [8,5,421,256]
    float* xB   = xA + (size_t)NB * 5 * PP;

    k_prep<<<NB, 128, 0, stream>>>(data_in, struc_in, meta_in, meta_out, sbuf);
    k_x0<<<842, 128, 0, stream>>>(rbf, hdc, cw, cb, sbuf, xA);

    for (int step = 0; step < STEPS; ++step) {
        const float* xi = (step & 1) ? xB : xA;
        float*       xo = (step & 1) ? xA : xB;
        k_nca<<<NB * JJ, 256, 0, stream>>>(xi, xo, w1, b1, w2, b2);
    }
    k_mean<<<NB * 5 * JJ, 256, 0, stream>>>(xA, mbuf);
    k_out<<<(5 * NB * 81 + 255) / 256, 256, 0, stream>>>(mbuf, out);
}

// Round 4
// 564.128 us; speedup vs baseline: 2.1373x; 2.1373x over previous
//
#include <hip/hip_runtime.h>
#include <math.h>

#define NB 8            // batch
#define JJ 421          // J = 5*81 + 16
#define HDCN 256        // HDC
#define PP (JJ*HDCN)    // 107776 pixels per (batch,channel) plane
#define STEPS 20

typedef __attribute__((ext_vector_type(8))) short bf16x8;
typedef __attribute__((ext_vector_type(4))) float f32x4;
typedef __attribute__((ext_vector_type(2))) float f32x2;
typedef __attribute__((ext_vector_type(4))) unsigned int uint4v;
typedef unsigned short ushort;
typedef unsigned int uint;

// ---- packed bf16 hi/lo state helpers (x ~ hi + lo, exact to ~2^-16 rel) ----
__device__ __forceinline__ uint splitpack(float x) {
    uint u = __float_as_uint(x);
    uint hib = u & 0xffff0000u;
    float r = x - __uint_as_float(hib);      // exact (Sterbenz)
    return hib | (__float_as_uint(r) >> 16);
}
__device__ __forceinline__ float unpack2(uint p) {
    return __uint_as_float(p & 0xffff0000u) + __uint_as_float(p << 16);
}
__device__ __forceinline__ float tanh_fast(float x) {
    float e = __expf(2.f * x);
    return 1.f - 2.f / (e + 1.f);            // inf-safe: x>>0 -> 1, x<<0 -> -1
}

__device__ __forceinline__ float wave_reduce_sum(float v) {
#pragma unroll
    for (int off = 32; off > 0; off >>= 1) v += __shfl_down(v, off);
    return v;
}

// ---------------------------------------------------------------------------
// k_wprep: precompute MFMA A-operand planes (w1 split to bf16 hi/lo, k=(c,dj)
// per dd slice) + packed [w2|b1] rows. Runs once, 1 block.
//   Ahi/Alo: [dd=3][oc=32][k=16] bf16;  Azr: 16 zeros;  w2p: [oc=32][8] f32
// ---------------------------------------------------------------------------
__global__ __launch_bounds__(256) void k_wprep(
    const float* __restrict__ w1, const float* __restrict__ b1,
    const float* __restrict__ w2,
    ushort* __restrict__ Ahi, ushort* __restrict__ Alo,
    ushort* __restrict__ Azr, float* __restrict__ w2p)
{
    int t = threadIdx.x;
    for (int idx = t; idx < 1536; idx += 256) {
        int dd = idx >> 9, rem = idx & 511, oc = rem >> 4, i = rem & 15;
        float w = (i < 15) ? w1[oc * 45 + i * 3 + dd] : 0.f;   // k=(c*3+dj), tap dd
        uint u = __float_as_uint(w);
        uint hib = u & 0xffff0000u;
        float r = w - __uint_as_float(hib);
        Ahi[idx] = (ushort)(hib >> 16);
        Alo[idx] = (ushort)(__float_as_uint(r) >> 16);
    }
    if (t < 16) Azr[t] = 0;
    {
        int oc = t >> 3, o = t & 7;
        float v = 0.f;
        if (o < 5) v = w2[o * 32 + oc];
        else if (o == 5) v = b1[oc];
        w2p[t] = v;
    }
}

// ---------------------------------------------------------------------------
// k_prep: s[b] = sum_i data[b,i], data = concat(data_input, structure, pe)
// ---------------------------------------------------------------------------
__global__ __launch_bounds__(128) void k_prep(
    const float* __restrict__ din, const float* __restrict__ stin,
    const float* __restrict__ m_in, const float* __restrict__ m_out,
    float* __restrict__ sbuf)
{
    int b = blockIdx.x, t = threadIdx.x;
    float acc = 0.f;
    for (int k = t; k < 324; k += 128) acc += din[b * 324 + k];
    for (int k = t; k < 81;  k += 128) acc += stin[b * 81 + k];
    if (t < 16) {
        int i = t;
        float pos_in  = m_in[b]  * 0.01f;
        float pos_out = m_out[b] * 0.01f;
        float div = powf(10000.0f, (float)(2 * (i / 2)) / 16.0f);
        float ai = pos_in / div, ao = pos_out / div;
        float v = ((i & 1) == 0) ? 0.5f * (sinf(ai) + cosf(ai))
                                 : 0.5f * (cosf(ai) + sinf(ao));
        acc += v;
    }
    __shared__ float part[2];
    float w = wave_reduce_sum(acc);
    if ((t & 63) == 0) part[t >> 6] = w;
    __syncthreads();
    if (t == 0) sbuf[b] = part[0] + part[1];
}

// ---------------------------------------------------------------------------
// k_x0: x0[b,o,jd] = tanh( A - 2p*B + p^2*C + cb[o] ), stored packed hi/lo
// ---------------------------------------------------------------------------
__global__ __launch_bounds__(128) void k_x0(
    const float* __restrict__ rbf, const float* __restrict__ hdc,
    const float* __restrict__ cw, const float* __restrict__ cb,
    const float* __restrict__ sbuf, uint* __restrict__ x0)
{
    __shared__ float wl[320];
    __shared__ float Cw[5];
    __shared__ float sb[8];
    __shared__ float cbs[5];
    int t = threadIdx.x;
    for (int k = t; k < 320; k += 128) wl[k] = cw[k];
    if (t < 8)   sb[t] = sbuf[t];
    if (t < 5)   cbs[t] = cb[t];
    __syncthreads();
    if (t < 5) { float c = 0.f; for (int r = 0; r < 64; ++r) c += wl[t * 64 + r]; Cw[t] = c; }
    __syncthreads();

    int jd = blockIdx.x * 128 + t;       // 842*128 == PP exactly
    float A[5]  = {0, 0, 0, 0, 0};
    float Bv[5] = {0, 0, 0, 0, 0};
    for (int r = 0; r < 64; ++r) {
        float v  = rbf[(size_t)r * PP + jd];
        float v2 = v * v;
#pragma unroll
        for (int o = 0; o < 5; ++o) {
            float w = wl[o * 64 + r];
            A[o]  = fmaf(w, v2, A[o]);
            Bv[o] = fmaf(w, v,  Bv[o]);
        }
    }
#pragma unroll
    for (int b = 0; b < 8; ++b) {
        float p  = sb[b] * hdc[(size_t)b * PP + jd];
        float p2 = p * p;
#pragma unroll
        for (int o = 0; o < 5; ++o) {
            float val = A[o] - 2.f * p * Bv[o] + p2 * Cw[o] + cbs[o];
            x0[(size_t)(b * 5 + o) * PP + jd] = splitpack(tanh_fast(val));
        }
    }
}

// ---------------------------------------------------------------------------
// k_nca: one NCA step, one (b, j) row of 256 px per block.
//   GEMM: M=32 oc, K=16 (c,dj) [hi & lo planes], N=256 px; the conv dd-shift
//   is absorbed into the B-fragment LDS ROW address (row = d + dd).
//   Bs row layout (64B): [xh k0..15 (32B) | xl k0..15 (32B)], 16B chunks
//   XOR-swizzled by ((row>>1)&3). Rows 0 and 257 are zero padding (d = -1,256).
//   Per dd: MFMA1 A=[wh|wl] B=[xh|xh]; MFMA2 A=[wh|0] B=[xl|*].
// ---------------------------------------------------------------------------
__global__ __launch_bounds__(256, 4) void k_nca(
    const uint* __restrict__ xin, uint* __restrict__ xout,
    const ushort* __restrict__ Ahi, const ushort* __restrict__ Alo,
    const ushort* __restrict__ Azr, const float* __restrict__ w2p,
    const float* __restrict__ b2)
{
    __shared__ uint Bs[258 * 16];        // 16.5 KB

    const int t = threadIdx.x;
    const int b = blockIdx.x & 7;        // XCD affinity: batch per XCD
    const int j = blockIdx.x >> 3;
    const int lane = t & 63, wv = t >> 6;
    const int m = lane & 15, gq = lane >> 4;

    // ---- A fragments from precomputed planes (12x dwordx4, L2-hot) ----
    bf16x8 A1[2][3], A2[2][3];
#pragma unroll
    for (int mt = 0; mt < 2; ++mt)
#pragma unroll
        for (int dd = 0; dd < 3; ++dd) {
            int oc = mt * 16 + m;
            int off = dd * 512 + oc * 16 + (gq & 1) * 8;
            const ushort* p1 = (gq < 2 ? Ahi : Alo) + off;
            A1[mt][dd] = *(const bf16x8*)p1;
            const ushort* p2 = (gq < 2) ? (Ahi + off) : Azr;
            A2[mt][dd] = *(const bf16x8*)p2;
        }

    // ---- build Bs: thread t owns pixel px=t -> row t+1 ----
    {
        const uint* xb = xin + (size_t)b * 5 * PP;
        uint v[16];
#pragma unroll
        for (int c = 0; c < 5; ++c)
#pragma unroll
            for (int dj = 0; dj < 3; ++dj) {
                int jj = j + dj - 1;
                uint val = 0;
                if (jj >= 0 && jj < JJ) val = xb[(size_t)(c * JJ + jj) * HDCN + t];
                v[c * 3 + dj] = val;
            }
        v[15] = 0;
        uint xh[8], xl[8];
#pragma unroll
        for (int w = 0; w < 8; ++w) {
            uint a = v[2 * w], c = v[2 * w + 1];
            xh[w] = (a >> 16) | (c & 0xffff0000u);   // bf16 hi parts, k=2w,2w+1
            xl[w] = (a & 0xffffu) | (c << 16);       // bf16 lo parts
        }
        int row = t + 1;
        int s = (row >> 1) & 3;
        uint* rb = Bs + row * 16;
        *(uint4v*)(rb + ((0 ^ s) << 2)) = (uint4v){xh[0], xh[1], xh[2], xh[3]};
        *(uint4v*)(rb + ((1 ^ s) << 2)) = (uint4v){xh[4], xh[5], xh[6], xh[7]};
        *(uint4v*)(rb + ((2 ^ s) << 2)) = (uint4v){xl[0], xl[1], xl[2], xl[3]};
        *(uint4v*)(rb + ((3 ^ s) << 2)) = (uint4v){xl[4], xl[5], xl[6], xl[7]};
        if (t < 2) {
            uint* zr = Bs + (t == 0 ? 0 : 257 * 16);
            uint4v z = (uint4v){0, 0, 0, 0};
            ((uint4v*)zr)[0] = z; ((uint4v*)zr)[1] = z;
            ((uint4v*)zr)[2] = z; ((uint4v*)zr)[3] = z;
        }
    }
    __syncthreads();

    // ---- MFMA loop: 4 n-tiles x 3 dd x 2 m-tiles x 2 precision terms ----
    f32x4 acc[2][4];
#pragma unroll
    for (int mt = 0; mt < 2; ++mt)
#pragma unroll
        for (int nt = 0; nt < 4; ++nt) acc[mt][nt] = (f32x4){0.f, 0.f, 0.f, 0.f};

#pragma unroll
    for (int nt = 0; nt < 4; ++nt) {
        int d = (wv << 6) + (nt << 4) + m;
#pragma unroll
        for (int dd = 0; dd < 3; ++dd) {
            int row = d + dd;                 // px = d + dd - 1, +1 pad offset
            int s2 = (row >> 1) & 3;
            const uint* rb = Bs + row * 16;
            bf16x8 Bh = *(const bf16x8*)(rb + ((((gq & 1)) ^ s2) << 2));
            bf16x8 Bl = *(const bf16x8*)(rb + (((2 | (gq & 1)) ^ s2) << 2));
            acc[0][nt] = __builtin_amdgcn_mfma_f32_16x16x32_bf16(A1[0][dd], Bh, acc[0][nt], 0, 0, 0);
            acc[1][nt] = __builtin_amdgcn_mfma_f32_16x16x32_bf16(A1[1][dd], Bh, acc[1][nt], 0, 0, 0);
            acc[0][nt] = __builtin_amdgcn_mfma_f32_16x16x32_bf16(A2[0][dd], Bl, acc[0][nt], 0, 0, 0);
            acc[1][nt] = __builtin_amdgcn_mfma_f32_16x16x32_bf16(A2[1][dd], Bl, acc[1][nt], 0, 0, 0);
        }
    }

    // ---- epilogue: h=relu(Y+b1); dx=W2 h; cross-gq reduce; residual ----
    float w2r[2][4][5], b1r[2][4];
#pragma unroll
    for (int mt = 0; mt < 2; ++mt)
#pragma unroll
        for (int i = 0; i < 4; ++i) {
            int oc = mt * 16 + gq * 4 + i;
            const float* wp = w2p + oc * 8;
            f32x4 a = *(const f32x4*)wp;
            f32x2 e = *(const f32x2*)(wp + 4);
            w2r[mt][i][0] = a[0]; w2r[mt][i][1] = a[1];
            w2r[mt][i][2] = a[2]; w2r[mt][i][3] = a[3];
            w2r[mt][i][4] = e[0]; b1r[mt][i] = e[1];
        }
    float b2r[5];
#pragma unroll
    for (int o = 0; o < 5; ++o) b2r[o] = b2[o];

    const size_t base_bj = (size_t)b * 5 * PP + (size_t)j * HDCN;
#pragma unroll
    for (int nt = 0; nt < 4; ++nt) {
        int px = (wv << 6) + (nt << 4) + m;
        float dx[5] = {0, 0, 0, 0, 0};
#pragma unroll
        for (int mt = 0; mt < 2; ++mt)
#pragma unroll
            for (int i = 0; i < 4; ++i) {
                float h = fmaxf(acc[mt][nt][i] + b1r[mt][i], 0.f);
#pragma unroll
                for (int o = 0; o < 5; ++o) dx[o] = fmaf(w2r[mt][i][o], h, dx[o]);
            }
#pragma unroll
        for (int o = 0; o < 5; ++o) {
            dx[o] += __shfl_xor(dx[o], 16);
            dx[o] += __shfl_xor(dx[o], 32);
        }
        if (gq == 0) {
#pragma unroll
            for (int o = 0; o < 4; ++o) {
                size_t idx = base_bj + (size_t)o * PP + px;
                float xf = unpack2(xin[idx]);
                xout[idx] = splitpack(xf + dx[o] + b2r[o]);
            }
        } else if (gq == 1) {
            size_t idx = base_bj + (size_t)4 * PP + px;
            float xf = unpack2(xin[idx]);
            xout[idx] = splitpack(xf + dx[4] + b2r[4]);
        }
    }
}

// ---------------------------------------------------------------------------
// k_mean: m[bc,j] = mean_d tanh(x[bc,j,d]) from packed state
// ---------------------------------------------------------------------------
__global__ __launch_bounds__(256) void k_mean(
    const uint* __restrict__ x, float* __restrict__ m)
{
    int idx = blockIdx.x;
    int t = threadIdx.x;
    float v = tanh_fast(unpack2(x[(size_t)idx * HDCN + t]));
    __shared__ float part[4];
    float w = wave_reduce_sum(v);
    if ((t & 63) == 0) part[t >> 6] = w;
    __syncthreads();
    if (t == 0) m[idx] = (part[0] + part[1] + part[2] + part[3]) * (1.0f / 256.0f);
}

// ---------------------------------------------------------------------------
// k_out: adaptive pool J=421 -> 81, outputs concat(r,g,b,a,s)
// ---------------------------------------------------------------------------
__global__ __launch_bounds__(256) void k_out(
    const float* __restrict__ m, float* __restrict__ out)
{
    int idx = blockIdx.x * 256 + threadIdx.x;
    if (idx >= 5 * NB * 81) return;
    int c = idx / (NB * 81);
    int rem = idx % (NB * 81);
    int b = rem / 81;
    int o = rem % 81;
    int s_ = (o * JJ) / 81;
    int e_ = ((o + 1) * JJ + 80) / 81;
    float acc = 0.f;
    for (int jj = s_; jj < e_; ++jj) acc += m[(b * 5 + c) * JJ + jj];
    out[idx] = acc / (float)(e_ - s_);
}

// ---------------------------------------------------------------------------
extern "C" void kernel_launch(void* const* d_in, const int* in_sizes, int n_in,
                              void* d_out, int out_size, void* d_ws, size_t ws_size,
                              hipStream_t stream) {
    const float* data_in  = (const float*)d_in[0];
    const float* struc_in = (const float*)d_in[1];
    const float* meta_in  = (const float*)d_in[2];
    const float* meta_out = (const float*)d_in[3];
    const float* rbf      = (const float*)d_in[4];
    const float* hdc      = (const float*)d_in[5];
    const float* cw       = (const float*)d_in[6];
    const float* cb       = (const float*)d_in[7];
    const float* w1       = (const float*)d_in[8];
    const float* b1       = (const float*)d_in[9];
    const float* w2       = (const float*)d_in[10];
    const float* b2       = (const float*)d_in[11];
    float* out = (float*)d_out;

    float* ws   = (float*)d_ws;
    float* sbuf = ws;                          // 8 floats
    float* mbuf = ws + 64;                     // 40*421 floats
    ushort* Ahi = (ushort*)(ws + 20480);       // 1536 ushorts
    ushort* Alo = Ahi + 1536;                  // 1536 ushorts
    ushort* Azr = Alo + 1536;                  // 16 zeros
    float* w2p  = ws + 22528;                  // 32*8 floats
    uint* xA = (uint*)(ws + 32768);            // [8,5,421,256] packed hi/lo
    uint* xB = xA + (size_t)NB * 5 * PP;

    k_wprep<<<1, 256, 0, stream>>>(w1, b1, w2, Ahi, Alo, Azr, w2p);
    k_prep<<<NB, 128, 0, stream>>>(data_in, struc_in, meta_in, meta_out, sbuf);
    k_x0<<<842, 128, 0, stream>>>(rbf, hdc, cw, cb, sbuf, xA);

    for (int step = 0; step < STEPS; ++step) {
        const uint* xi = (step & 1) ? xB : xA;
        uint*       xo = (step & 1) ? xA : xB;
        k_nca<<<NB * JJ, 256, 0, stream>>>(xi, xo, Ahi, Alo, Azr, w2p, b2);
    }
    k_mean<<<NB * 5 * JJ, 256, 0, stream>>>(xA, mbuf);
    k_out<<<(5 * NB * 81 + 255) / 256, 256, 0, stream>>>(mbuf, out);
}

// Round 5
// 523.788 us; speedup vs baseline: 2.3019x; 1.0770x over previous
//
#include <hip/hip_runtime.h>
#include <math.h>

#define NB 8            // batch
#define JJ 421          // J = 5*81 + 16
#define HDCN 256        // HDC
#define PP (JJ*HDCN)    // 107776 pixels per (batch,channel) plane
#define STEPS 20

typedef __attribute__((ext_vector_type(8))) short bf16x8;
typedef __attribute__((ext_vector_type(4))) float f32x4;
typedef __attribute__((ext_vector_type(2))) float f32x2;
typedef __attribute__((ext_vector_type(4))) unsigned int uint4v;
typedef __attribute__((ext_vector_type(2))) int int2v;
typedef unsigned short ushort;
typedef unsigned int uint;

// ---- bf16 helpers: RNE round, packed hi/lo state (x ~ hi + lo) ----
__device__ __forceinline__ ushort f2bf(float f) {
    union { float f; uint u; } a; a.f = f;
    uint r = 0x7fffu + ((a.u >> 16) & 1u);     // round-to-nearest-even
    return (ushort)((a.u + r) >> 16);
}
__device__ __forceinline__ uint splitpack(float x) {
    uint u = __float_as_uint(x);
    uint r = 0x7fffu + ((u >> 16) & 1u);
    uint hib = (u + r) & 0xffff0000u;          // RNE bf16 hi (float bits)
    float lo = x - __uint_as_float(hib);       // exact residual
    return hib | f2bf(lo);                     // [hi bf16 | lo bf16]
}
__device__ __forceinline__ float unpack2(uint p) {
    return __uint_as_float(p & 0xffff0000u) + __uint_as_float(p << 16);
}
__device__ __forceinline__ float tanh_fast(float x) {
    float e = __expf(2.f * x);
    return 1.f - 2.f / (e + 1.f);              // inf-safe
}
__device__ __forceinline__ float wave_reduce_sum(float v) {
#pragma unroll
    for (int off = 32; off > 0; off >>= 1) v += __shfl_down(v, off);
    return v;
}
// cross-half (+/-32 lanes) sum on the VALU pipe (falls back to shfl)
__device__ __forceinline__ float red32(float d) {
#if __has_builtin(__builtin_amdgcn_permlane32_swap)
    int2v pr = __builtin_amdgcn_permlane32_swap(__float_as_int(d), __float_as_int(d), false, false);
    return __int_as_float(pr.x) + __int_as_float(pr.y);
#else
    return d + __shfl_xor(d, 32);
#endif
}

// ---------------------------------------------------------------------------
// k_wprep: A-operand planes for 2-dd K-packing (bf16 RNE, K=32):
//   P01[oc][k]: k<16 -> tap tau=k, dd=0 ; k>=16 -> tau=k-16, dd=1   (tau=c*3+dj)
//   P2 [oc][k]: k<16 -> tau=k, dd=2 ; k>=16 -> 0
//   w2p[oc][8] = {w2[0..4][oc], b1[oc], 0, 0}
// ---------------------------------------------------------------------------
__global__ __launch_bounds__(256) void k_wprep(
    const float* __restrict__ w1, const float* __restrict__ b1,
    const float* __restrict__ w2,
    ushort* __restrict__ P01, ushort* __restrict__ P2, float* __restrict__ w2p)
{
    int t = threadIdx.x;
    for (int idx = t; idx < 1024; idx += 256) {
        int oc = idx >> 5, k = idx & 31;
        int tau = k & 15, ddb = (k >> 4);
        float v01 = 0.f, v2 = 0.f;
        if (tau < 15) {
            int base = oc * 45 + (tau / 3) * 9 + (tau % 3) * 3;
            v01 = w1[base + ddb];              // dd = 0 or 1
            if (ddb == 0) v2 = w1[base + 2];   // dd = 2 in low half only
        }
        P01[idx] = f2bf(v01);
        P2[idx]  = f2bf(v2);
    }
    int oc = t >> 3, o = t & 7;
    float v = 0.f;
    if (o < 5) v = w2[o * 32 + oc];
    else if (o == 5) v = b1[oc];
    w2p[t] = v;
}

// ---------------------------------------------------------------------------
// k_prep: s[b] = sum_i data[b,i], data = concat(data_input, structure, pe)
// ---------------------------------------------------------------------------
__global__ __launch_bounds__(128) void k_prep(
    const float* __restrict__ din, const float* __restrict__ stin,
    const float* __restrict__ m_in, const float* __restrict__ m_out,
    float* __restrict__ sbuf)
{
    int b = blockIdx.x, t = threadIdx.x;
    float acc = 0.f;
    for (int k = t; k < 324; k += 128) acc += din[b * 324 + k];
    for (int k = t; k < 81;  k += 128) acc += stin[b * 81 + k];
    if (t < 16) {
        int i = t;
        float pos_in  = m_in[b]  * 0.01f;
        float pos_out = m_out[b] * 0.01f;
        float div = powf(10000.0f, (float)(2 * (i / 2)) / 16.0f);
        float ai = pos_in / div, ao = pos_out / div;
        float v = ((i & 1) == 0) ? 0.5f * (sinf(ai) + cosf(ai))
                                 : 0.5f * (cosf(ai) + sinf(ao));
        acc += v;
    }
    __shared__ float part[2];
    float w = wave_reduce_sum(acc);
    if ((t & 63) == 0) part[t >> 6] = w;
    __syncthreads();
    if (t == 0) sbuf[b] = part[0] + part[1];
}

// ---------------------------------------------------------------------------
// k_x0: x0[b,o,jd] = tanh( A - 2p*B + p^2*C + cb[o] ), stored packed hi/lo
// ---------------------------------------------------------------------------
__global__ __launch_bounds__(128) void k_x0(
    const float* __restrict__ rbf, const float* __restrict__ hdc,
    const float* __restrict__ cw, const float* __restrict__ cb,
    const float* __restrict__ sbuf, uint* __restrict__ x0)
{
    __shared__ float wl[320];
    __shared__ float Cw[5];
    __shared__ float sb[8];
    __shared__ float cbs[5];
    int t = threadIdx.x;
    for (int k = t; k < 320; k += 128) wl[k] = cw[k];
    if (t < 8)   sb[t] = sbuf[t];
    if (t < 5)   cbs[t] = cb[t];
    __syncthreads();
    if (t < 5) { float c = 0.f; for (int r = 0; r < 64; ++r) c += wl[t * 64 + r]; Cw[t] = c; }
    __syncthreads();

    int jd = blockIdx.x * 128 + t;       // 842*128 == PP exactly
    float A[5]  = {0, 0, 0, 0, 0};
    float Bv[5] = {0, 0, 0, 0, 0};
    for (int r = 0; r < 64; ++r) {
        float v  = rbf[(size_t)r * PP + jd];
        float v2 = v * v;
#pragma unroll
        for (int o = 0; o < 5; ++o) {
            float w = wl[o * 64 + r];
            A[o]  = fmaf(w, v2, A[o]);
            Bv[o] = fmaf(w, v,  Bv[o]);
        }
    }
#pragma unroll
    for (int b = 0; b < 8; ++b) {
        float p  = sb[b] * hdc[(size_t)b * PP + jd];
        float p2 = p * p;
#pragma unroll
        for (int o = 0; o < 5; ++o) {
            float val = A[o] - 2.f * p * Bv[o] + p2 * Cw[o] + cbs[o];
            x0[(size_t)(b * 5 + o) * PP + jd] = splitpack(tanh_fast(val));
        }
    }
}

// ---------------------------------------------------------------------------
// k_nca: one NCA step, TWO consecutive j-rows per block (grid 8*211=1688).
//   GEMM per row: M=32 oc, K=32 (2-dd-packed), N=256 px.
//   MFMA terms per n-tile: A01*Bh(dd01) + A2*Bh(dd2) + A01*Bl(dd01) + A2*Bl(dd2)
//   -> 8 MFMAs, 4 single ds_read_b128 B-fragments.
//   Bs[r] row layout (64B): [xh k0..15 | xl k0..15], 16B chunks XOR-swizzled
//   by ((row>>1)&3); rows 0 and 257 are zero pads (d=-1,256).
// ---------------------------------------------------------------------------
__global__ __launch_bounds__(256, 4) void k_nca(
    const uint* __restrict__ xin, uint* __restrict__ xout,
    const ushort* __restrict__ P01, const ushort* __restrict__ P2,
    const float* __restrict__ w2p, const float* __restrict__ b2)
{
    __shared__ uint Bs[2][258 * 16];     // 33 KB

    const int t = threadIdx.x;
    const int b = blockIdx.x & 7;        // XCD affinity: batch per XCD
    const int pj = blockIdx.x >> 3;      // 0..210
    const int j0 = pj * 2;
    const bool has1 = (j0 + 1) < JJ;     // pj=210 -> lone row 420
    const int lane = t & 63, wv = t >> 6;
    const int m = lane & 15, gq = lane >> 4;

    // ---- A fragments (4x b128 global, L2-hot) ----
    bf16x8 A01[2], A2[2];
#pragma unroll
    for (int mt = 0; mt < 2; ++mt) {
        int off = (mt * 16 + m) * 32 + gq * 8;
        A01[mt] = *(const bf16x8*)(P01 + off);
        A2[mt]  = *(const bf16x8*)(P2 + off);
    }

    // ---- w2/b1/b2 (uniform or small per-lane) ----
    float w2r[2][4][5], b1r[2][4], b2r[5];
#pragma unroll
    for (int mt = 0; mt < 2; ++mt)
#pragma unroll
        for (int i = 0; i < 4; ++i) {
            int oc = mt * 16 + gq * 4 + i;
            const float* wp = w2p + oc * 8;
            f32x4 a = *(const f32x4*)wp;
            f32x2 e = *(const f32x2*)(wp + 4);
            w2r[mt][i][0] = a[0]; w2r[mt][i][1] = a[1];
            w2r[mt][i][2] = a[2]; w2r[mt][i][3] = a[3];
            w2r[mt][i][4] = e[0]; b1r[mt][i] = e[1];
        }
#pragma unroll
    for (int o = 0; o < 5; ++o) b2r[o] = b2[o];

    // ---- stage 4 input rows x 5 ch, build both Bs ----
    {
        const uint* xb = xin + (size_t)b * 5 * PP;
        uint v[5][4];
#pragma unroll
        for (int c = 0; c < 5; ++c)
#pragma unroll
            for (int rr = 0; rr < 4; ++rr) {
                int jj = j0 - 1 + rr;
                uint val = 0;
                if (jj >= 0 && jj < JJ) val = xb[(size_t)(c * JJ + jj) * HDCN + t];
                v[c][rr] = val;
            }
        const int row = t + 1;
        const int s = (row >> 1) & 3;
#pragma unroll
        for (int r = 0; r < 2; ++r) {
            if (r == 1 && !has1) break;
            uint xh[8], xl[8];
#pragma unroll
            for (int w = 0; w < 8; ++w) {
                int k0 = 2 * w, k1 = 2 * w + 1;
                uint a = (k0 < 15) ? v[k0 / 3][k0 % 3 + r] : 0u;
                uint c = (k1 < 15) ? v[k1 / 3][k1 % 3 + r] : 0u;
                xh[w] = (a >> 16) | (c & 0xffff0000u);
                xl[w] = (a & 0xffffu) | (c << 16);
            }
            uint* rb = &Bs[r][row * 16];
            *(uint4v*)(rb + ((0 ^ s) << 2)) = (uint4v){xh[0], xh[1], xh[2], xh[3]};
            *(uint4v*)(rb + ((1 ^ s) << 2)) = (uint4v){xh[4], xh[5], xh[6], xh[7]};
            *(uint4v*)(rb + ((2 ^ s) << 2)) = (uint4v){xl[0], xl[1], xl[2], xl[3]};
            *(uint4v*)(rb + ((3 ^ s) << 2)) = (uint4v){xl[4], xl[5], xl[6], xl[7]};
        }
        if (t < 4) {
            uint* zr = &Bs[t >> 1][(t & 1) ? 257 * 16 : 0];
            uint4v z = (uint4v){0, 0, 0, 0};
            ((uint4v*)zr)[0] = z; ((uint4v*)zr)[1] = z;
            ((uint4v*)zr)[2] = z; ((uint4v*)zr)[3] = z;
        }
    }
    __syncthreads();

    // ---- per output row: 32 MFMAs + epilogue ----
    const int ch = gq & 1, dsel = gq >> 1;
#pragma unroll
    for (int r = 0; r < 2; ++r) {
        if (r == 1 && !has1) break;
        const int j = j0 + r;

        f32x4 acc[2][4];
#pragma unroll
        for (int mt = 0; mt < 2; ++mt)
#pragma unroll
            for (int nt = 0; nt < 4; ++nt) acc[mt][nt] = (f32x4){0.f, 0.f, 0.f, 0.f};

#pragma unroll
        for (int nt = 0; nt < 4; ++nt) {
            int px = (wv << 6) + (nt << 4) + m;
            int r01 = px + dsel;             // Bs row for dd = gq>>1 (k-half select)
            int r2  = px + 2;                // Bs row for dd = 2
            int s01 = (r01 >> 1) & 3, s2 = (r2 >> 1) & 3;
            const uint* q01 = &Bs[r][r01 * 16];
            const uint* q2  = &Bs[r][r2 * 16];
            bf16x8 Bh01 = *(const bf16x8*)(q01 + ((ch ^ s01) << 2));
            bf16x8 Bh2  = *(const bf16x8*)(q2  + ((ch ^ s2) << 2));
            bf16x8 Bl01 = *(const bf16x8*)(q01 + (((2 | ch) ^ s01) << 2));
            bf16x8 Bl2  = *(const bf16x8*)(q2  + (((2 | ch) ^ s2) << 2));
            acc[0][nt] = __builtin_amdgcn_mfma_f32_16x16x32_bf16(A01[0], Bh01, acc[0][nt], 0, 0, 0);
            acc[1][nt] = __builtin_amdgcn_mfma_f32_16x16x32_bf16(A01[1], Bh01, acc[1][nt], 0, 0, 0);
            acc[0][nt] = __builtin_amdgcn_mfma_f32_16x16x32_bf16(A2[0],  Bh2,  acc[0][nt], 0, 0, 0);
            acc[1][nt] = __builtin_amdgcn_mfma_f32_16x16x32_bf16(A2[1],  Bh2,  acc[1][nt], 0, 0, 0);
            acc[0][nt] = __builtin_amdgcn_mfma_f32_16x16x32_bf16(A01[0], Bl01, acc[0][nt], 0, 0, 0);
            acc[1][nt] = __builtin_amdgcn_mfma_f32_16x16x32_bf16(A01[1], Bl01, acc[1][nt], 0, 0, 0);
            acc[0][nt] = __builtin_amdgcn_mfma_f32_16x16x32_bf16(A2[0],  Bl2,  acc[0][nt], 0, 0, 0);
            acc[1][nt] = __builtin_amdgcn_mfma_f32_16x16x32_bf16(A2[1],  Bl2,  acc[1][nt], 0, 0, 0);
        }

        const size_t base_bj = (size_t)b * 5 * PP + (size_t)j * HDCN;
#pragma unroll
        for (int nt = 0; nt < 4; ++nt) {
            int px = (wv << 6) + (nt << 4) + m;
            float dx[5] = {0, 0, 0, 0, 0};
#pragma unroll
            for (int mt = 0; mt < 2; ++mt)
#pragma unroll
                for (int i = 0; i < 4; ++i) {
                    float h = fmaxf(acc[mt][nt][i] + b1r[mt][i], 0.f);
#pragma unroll
                    for (int o = 0; o < 5; ++o) dx[o] = fmaf(w2r[mt][i][o], h, dx[o]);
                }
#pragma unroll
            for (int o = 0; o < 5; ++o) {
                dx[o] += __shfl_xor(dx[o], 16);
                dx[o] = red32(dx[o]);
            }
            if (gq == 0) {
#pragma unroll
                for (int o = 0; o < 4; ++o) {
                    size_t idx = base_bj + (size_t)o * PP + px;
                    float xf = unpack2(xin[idx]);
                    xout[idx] = splitpack(xf + dx[o] + b2r[o]);
                }
            } else if (gq == 1) {
                size_t idx = base_bj + (size_t)4 * PP + px;
                float xf = unpack2(xin[idx]);
                xout[idx] = splitpack(xf + dx[4] + b2r[4]);
            }
        }
    }
}

// ---------------------------------------------------------------------------
// k_mean: m[bc,j] = mean_d tanh(x[bc,j,d]) from packed state
// ---------------------------------------------------------------------------
__global__ __launch_bounds__(256) void k_mean(
    const uint* __restrict__ x, float* __restrict__ m)
{
    int idx = blockIdx.x;
    int t = threadIdx.x;
    float v = tanh_fast(unpack2(x[(size_t)idx * HDCN + t]));
    __shared__ float part[4];
    float w = wave_reduce_sum(v);
    if ((t & 63) == 0) part[t >> 6] = w;
    __syncthreads();
    if (t == 0) m[idx] = (part[0] + part[1] + part[2] + part[3]) * (1.0f / 256.0f);
}

// ---------------------------------------------------------------------------
// k_out: adaptive pool J=421 -> 81, outputs concat(r,g,b,a,s)
// ---------------------------------------------------------------------------
__global__ __launch_bounds__(256) void k_out(
    const float* __restrict__ m, float* __restrict__ out)
{
    int idx = blockIdx.x * 256 + threadIdx.x;
    if (idx >= 5 * NB * 81) return;
    int c = idx / (NB * 81);
    int rem = idx % (NB * 81);
    int b = rem / 81;
    int o = rem % 81;
    int s_ = (o * JJ) / 81;
    int e_ = ((o + 1) * JJ + 80) / 81;
    float acc = 0.f;
    for (int jj = s_; jj < e_; ++jj) acc += m[(b * 5 + c) * JJ + jj];
    out[idx] = acc / (float)(e_ - s_);
}

// ---------------------------------------------------------------------------
extern "C" void kernel_launch(void* const* d_in, const int* in_sizes, int n_in,
                              void* d_out, int out_size, void* d_ws, size_t ws_size,
                              hipStream_t stream) {
    const float* data_in  = (const float*)d_in[0];
    const float* struc_in = (const float*)d_in[1];
    const float* meta_in  = (const float*)d_in[2];
    const float* meta_out = (const float*)d_in[3];
    const float* rbf      = (const float*)d_in[4];
    const float* hdc      = (const float*)d_in[5];
    const float* cw       = (const float*)d_in[6];
    const float* cb       = (const float*)d_in[7];
    const float* w1       = (const float*)d_in[8];
    const float* b1       = (const float*)d_in[9];
    const float* w2       = (const float*)d_in[10];
    const float* b2       = (const float*)d_in[11];
    float* out = (float*)d_out;

    float* ws   = (float*)d_ws;
    float* sbuf = ws;                          // 8 floats
    float* mbuf = ws + 64;                     // 40*421 floats
    ushort* P01 = (ushort*)(ws + 20480);       // 1024 ushorts
    ushort* P2  = P01 + 1024;                  // 1024 ushorts
    float* w2p  = ws + 22528;                  // 256 floats
    uint* xA = (uint*)(ws + 32768);            // [8,5,421,256] packed hi/lo
    uint* xB = xA + (size_t)NB * 5 * PP;

    k_wprep<<<1, 256, 0, stream>>>(w1, b1, w2, P01, P2, w2p);
    k_prep<<<NB, 128, 0, stream>>>(data_in, struc_in, meta_in, meta_out, sbuf);
    k_x0<<<842, 128, 0, stream>>>(rbf, hdc, cw, cb, sbuf, xA);

    for (int step = 0; step < STEPS; ++step) {
        const uint* xi = (step & 1) ? xB : xA;
        uint*       xo = (step & 1) ? xA : xB;
        k_nca<<<NB * 211, 256, 0, stream>>>(xi, xo, P01, P2, w2p, b2);
    }
    k_mean<<<NB * 5 * JJ, 256, 0, stream>>>(xA, mbuf);
    k_out<<<(5 * NB * 81 + 255) / 256, 256, 0, stream>>>(mbuf, out);
}

// Round 6
// 410.787 us; speedup vs baseline: 2.9352x; 1.2751x over previous
//
#include <hip/hip_runtime.h>
#include <math.h>

#define NB 8            // batch
#define JJ 421          // J = 5*81 + 16
#define HDCN 256        // HDC
#define PP (JJ*HDCN)    // 107776 pixels per (batch,channel) plane
#define STEPS 20

typedef __attribute__((ext_vector_type(8))) short bf16x8;
typedef __attribute__((ext_vector_type(4))) float f32x4;
typedef __attribute__((ext_vector_type(2))) float f32x2;
typedef __attribute__((ext_vector_type(4))) unsigned int uint4v;
typedef __attribute__((ext_vector_type(2))) int int2v;
typedef unsigned short ushort;
typedef unsigned int uint;

// ---- bf16 helpers: RNE round, packed hi/lo state (x ~ hi + lo) ----
__device__ __forceinline__ ushort f2bf(float f) {
    union { float f; uint u; } a; a.f = f;
    uint r = 0x7fffu + ((a.u >> 16) & 1u);     // round-to-nearest-even
    return (ushort)((a.u + r) >> 16);
}
__device__ __forceinline__ uint splitpack(float x) {
    uint u = __float_as_uint(x);
    uint r = 0x7fffu + ((u >> 16) & 1u);
    uint hib = (u + r) & 0xffff0000u;          // RNE bf16 hi (float bits)
    float lo = x - __uint_as_float(hib);       // exact residual
    return hib | f2bf(lo);                     // [hi bf16 | lo bf16]
}
__device__ __forceinline__ float unpack2(uint p) {
    return __uint_as_float(p & 0xffff0000u) + __uint_as_float(p << 16);
}
__device__ __forceinline__ float tanh_fast(float x) {
    float e = __expf(2.f * x);
    return 1.f - 2.f / (e + 1.f);              // inf-safe
}
__device__ __forceinline__ float wave_reduce_sum(float v) {
#pragma unroll
    for (int off = 32; off > 0; off >>= 1) v += __shfl_down(v, off);
    return v;
}
// cross-half (+/-32 lanes) sum on the VALU pipe (falls back to shfl)
__device__ __forceinline__ float red32(float d) {
#if __has_builtin(__builtin_amdgcn_permlane32_swap)
    int2v pr = __builtin_amdgcn_permlane32_swap(__float_as_int(d), __float_as_int(d), false, false);
    return __int_as_float(pr.x) + __int_as_float(pr.y);
#else
    return d + __shfl_xor(d, 32);
#endif
}

// ---------------------------------------------------------------------------
// k_wprep: A-operand planes, 3-plane K-repack (bf16 RNE, K=32 per plane):
//   plane p = dd; k-groups of 8: [hi tau 0-7 | hi tau 8-14 | lo tau 0-7 |
//   lo tau 8-14]  (tau = c*3+dj; w value independent of hi/lo group)
//   Pw[p][oc][k] = w1[oc, tau=k&15, dd=p]  (tau 15 -> 0 pad)
//   w2p[oc][8] = {w2[0..4][oc], b1[oc], 0, 0}
// ---------------------------------------------------------------------------
__global__ __launch_bounds__(256) void k_wprep(
    const float* __restrict__ w1, const float* __restrict__ b1,
    const float* __restrict__ w2,
    ushort* __restrict__ Pw, float* __restrict__ w2p)
{
    int t = threadIdx.x;
    for (int idx = t; idx < 3072; idx += 256) {
        int p = idx >> 10, rem = idx & 1023, oc = rem >> 5, k = rem & 31;
        int tau = k & 15;
        float v = 0.f;
        if (tau < 15) v = w1[oc * 45 + (tau / 3) * 9 + (tau % 3) * 3 + p];
        Pw[idx] = f2bf(v);
    }
    int oc = t >> 3, o = t & 7;
    float v = 0.f;
    if (o < 5) v = w2[o * 32 + oc];
    else if (o == 5) v = b1[oc];
    w2p[t] = v;
}

// ---------------------------------------------------------------------------
// k_prep: s[b] = sum_i data[b,i], data = concat(data_input, structure, pe)
// ---------------------------------------------------------------------------
__global__ __launch_bounds__(128) void k_prep(
    const float* __restrict__ din, const float* __restrict__ stin,
    const float* __restrict__ m_in, const float* __restrict__ m_out,
    float* __restrict__ sbuf)
{
    int b = blockIdx.x, t = threadIdx.x;
    float acc = 0.f;
    for (int k = t; k < 324; k += 128) acc += din[b * 324 + k];
    for (int k = t; k < 81;  k += 128) acc += stin[b * 81 + k];
    if (t < 16) {
        int i = t;
        float pos_in  = m_in[b]  * 0.01f;
        float pos_out = m_out[b] * 0.01f;
        float div = powf(10000.0f, (float)(2 * (i / 2)) / 16.0f);
        float ai = pos_in / div, ao = pos_out / div;
        float v = ((i & 1) == 0) ? 0.5f * (sinf(ai) + cosf(ai))
                                 : 0.5f * (cosf(ai) + sinf(ao));
        acc += v;
    }
    __shared__ float part[2];
    float w = wave_reduce_sum(acc);
    if ((t & 63) == 0) part[t >> 6] = w;
    __syncthreads();
    if (t == 0) sbuf[b] = part[0] + part[1];
}

// ---------------------------------------------------------------------------
// k_x0: x0[b,o,jd] = tanh( A - 2p*B + p^2*C + cb[o] ), stored packed hi/lo
// ---------------------------------------------------------------------------
__global__ __launch_bounds__(128) void k_x0(
    const float* __restrict__ rbf, const float* __restrict__ hdc,
    const float* __restrict__ cw, const float* __restrict__ cb,
    const float* __restrict__ sbuf, uint* __restrict__ x0)
{
    __shared__ float wl[320];
    __shared__ float Cw[5];
    __shared__ float sb[8];
    __shared__ float cbs[5];
    int t = threadIdx.x;
    for (int k = t; k < 320; k += 128) wl[k] = cw[k];
    if (t < 8)   sb[t] = sbuf[t];
    if (t < 5)   cbs[t] = cb[t];
    __syncthreads();
    if (t < 5) { float c = 0.f; for (int r = 0; r < 64; ++r) c += wl[t * 64 + r]; Cw[t] = c; }
    __syncthreads();

    int jd = blockIdx.x * 128 + t;       // 842*128 == PP exactly
    float A[5]  = {0, 0, 0, 0, 0};
    float Bv[5] = {0, 0, 0, 0, 0};
    for (int r = 0; r < 64; ++r) {
        float v  = rbf[(size_t)r * PP + jd];
        float v2 = v * v;
#pragma unroll
        for (int o = 0; o < 5; ++o) {
            float w = wl[o * 64 + r];
            A[o]  = fmaf(w, v2, A[o]);
            Bv[o] = fmaf(w, v,  Bv[o]);
        }
    }
#pragma unroll
    for (int b = 0; b < 8; ++b) {
        float p  = sb[b] * hdc[(size_t)b * PP + jd];
        float p2 = p * p;
#pragma unroll
        for (int o = 0; o < 5; ++o) {
            float val = A[o] - 2.f * p * Bv[o] + p2 * Cw[o] + cbs[o];
            x0[(size_t)(b * 5 + o) * PP + jd] = splitpack(tanh_fast(val));
        }
    }
}

// ---------------------------------------------------------------------------
// k_nca: one NCA step, TWO consecutive j-rows per block (grid 8*211=1688).
//   GEMM per row: M=32 oc, K=96 (3 planes of K=32), N=256 px.
//   Plane p = dd; k-groups = [xh 0-7 | xh 8-14 | xl 0-7 | xl 8-14] ->
//   B-frag chunk index = gq, row = px + p. 3 ds_read_b128 + 6 MFMAs per nt.
//   Bs row layout (64B): [xh(2 chunks) | xl(2 chunks)], chunks XOR-swizzled
//   by ((row>>1)&3); rows 0 and 257 are zero pads (d=-1,256).
//   Epilogue: fp32 fma-chain W2 + shuffle reduce, dx bounced through
//   wave-local LDS so the final store is coalesced and uses the staged
//   residual (no xin re-read).
// ---------------------------------------------------------------------------
__global__ __launch_bounds__(256, 3) void k_nca(
    const uint* __restrict__ xin, uint* __restrict__ xout,
    const ushort* __restrict__ Pw, const float* __restrict__ w2p,
    const float* __restrict__ b2)
{
    __shared__ uint Bs[2][258 * 16];     // 33 KB
    __shared__ float Ds[4][5][64];       //  5 KB (per-wave dx bounce)

    const int t = threadIdx.x;
    const int b = blockIdx.x & 7;        // XCD affinity: batch per XCD
    const int pj = blockIdx.x >> 3;      // 0..210
    const int j0 = pj * 2;
    const bool has1 = (j0 + 1) < JJ;     // pj=210 -> lone row 420
    const int lane = t & 63, wv = t >> 6;
    const int m = lane & 15, gq = lane >> 4;

    // ---- A fragments (6x b128 global, L2-hot) ----
    bf16x8 Ap[3][2];
#pragma unroll
    for (int p = 0; p < 3; ++p)
#pragma unroll
        for (int mt = 0; mt < 2; ++mt)
            Ap[p][mt] = *(const bf16x8*)(Pw + p * 1024 + (mt * 16 + m) * 32 + gq * 8);

    // ---- w2/b1/b2 ----
    float w2r[2][4][5], b1r[2][4], b2r[5];
#pragma unroll
    for (int mt = 0; mt < 2; ++mt)
#pragma unroll
        for (int i = 0; i < 4; ++i) {
            int oc = mt * 16 + gq * 4 + i;
            const float* wp = w2p + oc * 8;
            f32x4 a = *(const f32x4*)wp;
            f32x2 e = *(const f32x2*)(wp + 4);
            w2r[mt][i][0] = a[0]; w2r[mt][i][1] = a[1];
            w2r[mt][i][2] = a[2]; w2r[mt][i][3] = a[3];
            w2r[mt][i][4] = e[0]; b1r[mt][i] = e[1];
        }
#pragma unroll
    for (int o = 0; o < 5; ++o) b2r[o] = b2[o];

    // ---- stage 4 input rows x 5 ch, build both Bs ----
    uint v[5][4];
    {
        const uint* xb = xin + (size_t)b * 5 * PP;
#pragma unroll
        for (int c = 0; c < 5; ++c)
#pragma unroll
            for (int rr = 0; rr < 4; ++rr) {
                int jj = j0 - 1 + rr;
                uint val = 0;
                if (jj >= 0 && jj < JJ) val = xb[(size_t)(c * JJ + jj) * HDCN + t];
                v[c][rr] = val;
            }
        const int row = t + 1;
        const int s = (row >> 1) & 3;
#pragma unroll
        for (int r = 0; r < 2; ++r) {
            if (r == 1 && !has1) break;
            uint xh[8], xl[8];
#pragma unroll
            for (int w = 0; w < 8; ++w) {
                int k0 = 2 * w, k1 = 2 * w + 1;
                uint a = (k0 < 15) ? v[k0 / 3][k0 % 3 + r] : 0u;
                uint c = (k1 < 15) ? v[k1 / 3][k1 % 3 + r] : 0u;
                xh[w] = (a >> 16) | (c & 0xffff0000u);
                xl[w] = (a & 0xffffu) | (c << 16);
            }
            uint* rb = &Bs[r][row * 16];
            *(uint4v*)(rb + ((0 ^ s) << 2)) = (uint4v){xh[0], xh[1], xh[2], xh[3]};
            *(uint4v*)(rb + ((1 ^ s) << 2)) = (uint4v){xh[4], xh[5], xh[6], xh[7]};
            *(uint4v*)(rb + ((2 ^ s) << 2)) = (uint4v){xl[0], xl[1], xl[2], xl[3]};
            *(uint4v*)(rb + ((3 ^ s) << 2)) = (uint4v){xl[4], xl[5], xl[6], xl[7]};
        }
        if (t < 4) {
            uint* zr = &Bs[t >> 1][(t & 1) ? 257 * 16 : 0];
            uint4v z = (uint4v){0, 0, 0, 0};
            ((uint4v*)zr)[0] = z; ((uint4v*)zr)[1] = z;
            ((uint4v*)zr)[2] = z; ((uint4v*)zr)[3] = z;
        }
    }
    __syncthreads();

    // ---- per output row: 24 MFMAs + epilogue ----
#pragma unroll
    for (int r = 0; r < 2; ++r) {
        if (r == 1 && !has1) break;
        const int j = j0 + r;

        f32x4 acc[2][4];
#pragma unroll
        for (int mt = 0; mt < 2; ++mt)
#pragma unroll
            for (int nt = 0; nt < 4; ++nt) acc[mt][nt] = (f32x4){0.f, 0.f, 0.f, 0.f};

#pragma unroll
        for (int nt = 0; nt < 4; ++nt) {
            int px = (wv << 6) + (nt << 4) + m;
#pragma unroll
            for (int p = 0; p < 3; ++p) {
                int row = px + p;
                int s2 = (row >> 1) & 3;
                bf16x8 Bf = *(const bf16x8*)(&Bs[r][row * 16] + ((gq ^ s2) << 2));
                acc[0][nt] = __builtin_amdgcn_mfma_f32_16x16x32_bf16(Ap[p][0], Bf, acc[0][nt], 0, 0, 0);
                acc[1][nt] = __builtin_amdgcn_mfma_f32_16x16x32_bf16(Ap[p][1], Bf, acc[1][nt], 0, 0, 0);
            }
        }

        // W2 projection (fp32 fma chain) + cross-lane reduce + LDS bounce
#pragma unroll
        for (int nt = 0; nt < 4; ++nt) {
            float dx[5] = {0, 0, 0, 0, 0};
#pragma unroll
            for (int mt = 0; mt < 2; ++mt)
#pragma unroll
                for (int i = 0; i < 4; ++i) {
                    float h = fmaxf(acc[mt][nt][i] + b1r[mt][i], 0.f);
#pragma unroll
                    for (int o = 0; o < 5; ++o) dx[o] = fmaf(w2r[mt][i][o], h, dx[o]);
                }
#pragma unroll
            for (int o = 0; o < 5; ++o) {
                dx[o] += __shfl_xor(dx[o], 16);
                dx[o] = red32(dx[o]);
            }
            int col = (nt << 4) + m;
            if (gq == 0) {
#pragma unroll
                for (int o = 0; o < 4; ++o) Ds[wv][o][col] = dx[o];
            } else if (gq == 1) {
                Ds[wv][4][col] = dx[4];
            }
        }

        // coalesced store: residual from staged v, dx from wave-local LDS
        const size_t base_bj = (size_t)b * 5 * PP + (size_t)j * HDCN;
#pragma unroll
        for (int c = 0; c < 5; ++c) {
            float d = Ds[wv][c][lane];
            float xn = unpack2(v[c][r + 1]) + d + b2r[c];
            xout[base_bj + (size_t)c * PP + t] = splitpack(xn);
        }
    }
}

// ---------------------------------------------------------------------------
// k_mean: m[bc,j] = mean_d tanh(x[bc,j,d]); 8 j-rows per block, 32 thr/row
// ---------------------------------------------------------------------------
__global__ __launch_bounds__(256) void k_mean(
    const uint* __restrict__ x, float* __restrict__ m)
{
    int bc = blockIdx.x / 53, jblk = blockIdx.x % 53;
    int t = threadIdx.x;
    int jr = jblk * 8 + (t >> 5);
    if (jr >= JJ) return;
    const uint* p = x + (size_t)bc * PP + (size_t)jr * HDCN + (t & 31) * 8;
    uint4v u0 = *(const uint4v*)p;
    uint4v u1 = *(const uint4v*)(p + 4);
    float s = 0.f;
#pragma unroll
    for (int k = 0; k < 4; ++k) s += tanh_fast(unpack2(u0[k]));
#pragma unroll
    for (int k = 0; k < 4; ++k) s += tanh_fast(unpack2(u1[k]));
#pragma unroll
    for (int off = 16; off > 0; off >>= 1) s += __shfl_down(s, off, 32);
    if ((t & 31) == 0) m[bc * JJ + jr] = s * (1.0f / 256.0f);
}

// ---------------------------------------------------------------------------
// k_out: adaptive pool J=421 -> 81, outputs concat(r,g,b,a,s)
// ---------------------------------------------------------------------------
__global__ __launch_bounds__(256) void k_out(
    const float* __restrict__ m, float* __restrict__ out)
{
    int idx = blockIdx.x * 256 + threadIdx.x;
    if (idx >= 5 * NB * 81) return;
    int c = idx / (NB * 81);
    int rem = idx % (NB * 81);
    int b = rem / 81;
    int o = rem % 81;
    int s_ = (o * JJ) / 81;
    int e_ = ((o + 1) * JJ + 80) / 81;
    float acc = 0.f;
    for (int jj = s_; jj < e_; ++jj) acc += m[(b * 5 + c) * JJ + jj];
    out[idx] = acc / (float)(e_ - s_);
}

// ---------------------------------------------------------------------------
extern "C" void kernel_launch(void* const* d_in, const int* in_sizes, int n_in,
                              void* d_out, int out_size, void* d_ws, size_t ws_size,
                              hipStream_t stream) {
    const float* data_in  = (const float*)d_in[0];
    const float* struc_in = (const float*)d_in[1];
    const float* meta_in  = (const float*)d_in[2];
    const float* meta_out = (const float*)d_in[3];
    const float* rbf      = (const float*)d_in[4];
    const float* hdc      = (const float*)d_in[5];
    const float* cw       = (const float*)d_in[6];
    const float* cb       = (const float*)d_in[7];
    const float* w1       = (const float*)d_in[8];
    const float* b1       = (const float*)d_in[9];
    const float* w2       = (const float*)d_in[10];
    const float* b2       = (const float*)d_in[11];
    float* out = (float*)d_out;

    float* ws   = (float*)d_ws;
    float* sbuf = ws;                          // 8 floats
    float* mbuf = ws + 64;                     // 40*421 floats
    ushort* Pw  = (ushort*)(ws + 20480);       // 3072 ushorts (3 planes)
    float* w2p  = ws + 22528;                  // 256 floats
    uint* xA = (uint*)(ws + 32768);            // [8,5,421,256] packed hi/lo
    uint* xB = xA + (size_t)NB * 5 * PP;

    k_wprep<<<1, 256, 0, stream>>>(w1, b1, w2, Pw, w2p);
    k_prep<<<NB, 128, 0, stream>>>(data_in, struc_in, meta_in, meta_out, sbuf);
    k_x0<<<842, 128, 0, stream>>>(rbf, hdc, cw, cb, sbuf, xA);

    for (int step = 0; step < STEPS; ++step) {
        const uint* xi = (step & 1) ? xB : xA;
        uint*       xo = (step & 1) ? xA : xB;
        k_nca<<<NB * 211, 256, 0, stream>>>(xi, xo, Pw, w2p, b2);
    }
    k_mean<<<(40 * 53), 256, 0, stream>>>(xA, mbuf);
    k_out<<<(5 * NB * 81 + 255) / 256, 256, 0, stream>>>(mbuf, out);
}